// Round 1
// 199.372 us; speedup vs baseline: 1.0691x; 1.0691x over previous
//
#include <hip/hip_runtime.h>
#include <math.h>

#define NM 131072
#define PP 256
#define BB 32

#define INF_F 3.0e38f
#define LDW 13         // padded LDS stride for knnB sub-merge (13 coprime 32)

#define KA_BLOCKS 256  // fused_knn: one block per pivot (knnA role)
#define KB_BLOCKS 512  // fused_knn: 256 mesh points per block (knnB role)

// Branchless sorted insert into (d0<=d1<=d2) top-3 list.
// Strict < : on exact ties the incumbent (earlier-scanned = lower index) wins.
// Valid ONLY when candidates arrive in ascending index order (per-thread scans).
__device__ __forceinline__ void ins3(float d, int i,
    float& d0, float& d1, float& d2, int& i0, int& i1, int& i2) {
  bool l0 = d < d0, l1 = d < d1, l2 = d < d2;
  d2 = l1 ? d1 : (l2 ? d : d2);
  i2 = l1 ? i1 : (l2 ? i : i2);
  d1 = l0 ? d0 : (l1 ? d : d1);
  i1 = l0 ? i0 : (l1 ? i : i1);
  d0 = l0 ? d : d0;
  i0 = l0 ? i : i0;
}

// Tie-aware compare for merge phases where index ranges interleave:
// lower index wins on exact distance tie (lax.top_k stable order).
__device__ __forceinline__ bool lt2(float d, int i, float D, int I) {
  return (d < D) || (d == D && i < I);
}

__device__ __forceinline__ void ins3t(float d, int i,
    float& d0, float& d1, float& d2, int& i0, int& i1, int& i2) {
  bool l0 = lt2(d, i, d0, i0), l1 = lt2(d, i, d1, i1), l2 = lt2(d, i, d2, i2);
  d2 = l1 ? d1 : (l2 ? d : d2);
  i2 = l1 ? i1 : (l2 ? i : i2);
  d1 = l0 ? d0 : (l1 ? d : d1);
  i1 = l0 ? i0 : (l1 ? i : i1);
  d0 = l0 ? d : d0;
  i0 = l0 ? i : i0;
}

// Exact-fp32 distance matching the reference's (a-b)^2 + (c-d)^2 (no fma contraction).
__device__ __forceinline__ float dist2(float ax, float ay, float bx, float by) {
  float dx = ax - bx, dy = ay - by;
  return __fadd_rn(__fmul_rn(dx, dx), __fmul_rn(dy, dy));
}

// ---------- fused KNN: knnA (per-pivot) + knnB (per-mesh) + y2 zero, ONE launch ----------
// blocks [0,256): knnA, block = pivot p. 1024 threads scan all 131072 mesh points
//   (thread t: indices t, t+1024, ... -> coalesced 512B/wave float2 loads; mesh is
//   1 MB so replays hit L2). LDS tree-merge 1024->128->16->1, tie-aware.
// blocks [256,768): knnB, block = 256 mesh points x 4 pivot-subranges (old knnB_out
//   phase 1, unchanged semantics: sub ranges merged in ascending range order).
// block 768: zero y2 (replaces the hipMemsetAsync dispatch).
__global__ __launch_bounds__(1024)
void fused_knn(const float* __restrict__ mesh, const float* __restrict__ piv,
               float* __restrict__ wA, int* __restrict__ idxA,
               float* __restrict__ wB, int* __restrict__ idxB,
               float* __restrict__ y2) {
  const int blk = blockIdx.x;
  const int tid = threadIdx.x;
  __shared__ float sdf[PP * LDW];   // 3328 floats: covers knnB (256*13) and knnA (1024*3)
  __shared__ int   sif[PP * LDW];

  if (blk < KA_BLOCKS) {
    // ---- knnA role: pivot p vs all mesh points ----
    const int p = blk;
    const float2 pv = ((const float2*)piv)[p];          // wave-uniform broadcast
    const float2* m2 = (const float2*)mesh;
    float d0 = INF_F, d1 = INF_F, d2 = INF_F;
    int i0 = 0, i1 = 0, i2 = 0;
#pragma unroll 4
    for (int j = 0; j < 128; ++j) {
      int idx = tid + (j << 10);                        // ascending per thread
      float2 mp = m2[idx];                              // coalesced
      ins3(dist2(pv.x, pv.y, mp.x, mp.y), idx, d0, d1, d2, i0, i1, i2);
    }
    sdf[tid * 3 + 0] = d0; sif[tid * 3 + 0] = i0;
    sdf[tid * 3 + 1] = d1; sif[tid * 3 + 1] = i1;
    sdf[tid * 3 + 2] = d2; sif[tid * 3 + 2] = i2;
    __syncthreads();

    // L1: 1024 -> 128 (each of 128 threads merges slots {t+128s}; writes own slot t,
    // which no other thread reads -> no extra barrier needed inside the level)
    if (tid < 128) {
      float e0 = INF_F, e1 = INF_F, e2 = INF_F; int j0 = 0, j1 = 0, j2 = 0;
#pragma unroll
      for (int s = 0; s < 8; ++s) {
        int o = (tid + 128 * s) * 3;
#pragma unroll
        for (int k = 0; k < 3; ++k) ins3t(sdf[o + k], sif[o + k], e0, e1, e2, j0, j1, j2);
      }
      sdf[tid * 3 + 0] = e0; sif[tid * 3 + 0] = j0;
      sdf[tid * 3 + 1] = e1; sif[tid * 3 + 1] = j1;
      sdf[tid * 3 + 2] = e2; sif[tid * 3 + 2] = j2;
    }
    __syncthreads();

    // L2: 128 -> 16
    if (tid < 16) {
      float e0 = INF_F, e1 = INF_F, e2 = INF_F; int j0 = 0, j1 = 0, j2 = 0;
#pragma unroll
      for (int s = 0; s < 8; ++s) {
        int o = (tid + 16 * s) * 3;
#pragma unroll
        for (int k = 0; k < 3; ++k) ins3t(sdf[o + k], sif[o + k], e0, e1, e2, j0, j1, j2);
      }
      sdf[tid * 3 + 0] = e0; sif[tid * 3 + 0] = j0;
      sdf[tid * 3 + 1] = e1; sif[tid * 3 + 1] = j1;
      sdf[tid * 3 + 2] = e2; sif[tid * 3 + 2] = j2;
    }
    __syncthreads();

    // L3: 16 -> 1, write final weights/indices
    if (tid == 0) {
      float e0 = INF_F, e1 = INF_F, e2 = INF_F; int j0 = 0, j1 = 0, j2 = 0;
      for (int s = 0; s < 16; ++s) {
        int o = s * 3;
#pragma unroll
        for (int k = 0; k < 3; ++k) ins3t(sdf[o + k], sif[o + k], e0, e1, e2, j0, j1, j2);
      }
      wA[p * 3 + 0] = 1.0f / fmaxf(e0, 1e-16f); idxA[p * 3 + 0] = j0;
      wA[p * 3 + 1] = 1.0f / fmaxf(e1, 1e-16f); idxA[p * 3 + 1] = j1;
      wA[p * 3 + 2] = 1.0f / fmaxf(e2, 1e-16f); idxA[p * 3 + 2] = j2;
    }
  } else if (blk < KA_BLOCKS + KB_BLOCKS) {
    // ---- knnB role: 256 mesh points, each vs all 256 pivots (4 subranges) ----
    const int bi = blk - KA_BLOCKS;
    const int ml = tid & 255;
    const int sub = tid >> 8;                           // wave-uniform
    const int m = bi * 256 + ml;
    const float2 mv = ((const float2*)mesh)[m];         // coalesced per-lane
    float d0 = INF_F, d1 = INF_F, d2 = INF_F;
    int i0 = 0, i1 = 0, i2 = 0;
    const int base = sub * 64;
#pragma unroll 4
    for (int i = 0; i < 64; ++i) {
      int idx = base + i;
      float px = piv[2 * idx], py = piv[2 * idx + 1];   // wave-uniform -> scalar
      ins3(dist2(mv.x, mv.y, px, py), idx, d0, d1, d2, i0, i1, i2);
    }
    sdf[ml * LDW + sub * 3 + 0] = d0; sif[ml * LDW + sub * 3 + 0] = i0;
    sdf[ml * LDW + sub * 3 + 1] = d1; sif[ml * LDW + sub * 3 + 1] = i1;
    sdf[ml * LDW + sub * 3 + 2] = d2; sif[ml * LDW + sub * 3 + 2] = i2;
    __syncthreads();

    if (tid < 256) {
      // merge sub 0..3 in ascending range order: strict < keeps exact tie-break
      float e0 = sdf[tid * LDW + 0], e1 = sdf[tid * LDW + 1], e2 = sdf[tid * LDW + 2];
      int j0 = sif[tid * LDW + 0], j1 = sif[tid * LDW + 1], j2 = sif[tid * LDW + 2];
#pragma unroll
      for (int s = 1; s < 4; ++s)
#pragma unroll
        for (int k = 0; k < 3; ++k)
          ins3(sdf[tid * LDW + s * 3 + k], sif[tid * LDW + s * 3 + k], e0, e1, e2, j0, j1, j2);
      const int m0 = bi * 256 + tid;
      wB[m0 * 3 + 0] = 1.0f / fmaxf(e0, 1e-16f); idxB[m0 * 3 + 0] = j0;
      wB[m0 * 3 + 1] = 1.0f / fmaxf(e1, 1e-16f); idxB[m0 * 3 + 1] = j1;
      wB[m0 * 3 + 2] = 1.0f / fmaxf(e2, 1e-16f); idxB[m0 * 3 + 2] = j2;
    }
  } else {
    // ---- zero y2 (BB*PP*3 = 24576 floats = 6144 float4) ----
    float4 z; z.x = 0.f; z.y = 0.f; z.z = 0.f; z.w = 0.f;
    float4* p4 = (float4*)y2;
#pragma unroll
    for (int j = 0; j < 6; ++j) p4[tid + (j << 10)] = z;
  }
}

// ---------- fused gather+LN+interp + q/Q/K projection ----------
// Phase A (8 threads): old gather_ln body for the block's 8 pivot rows -> LDS + global y.
// Phase B/C: old qqk_kernel unchanged, reading y rows from LDS.
// __launch_bounds__(128, 2): VGPR budget 256/wave so wreg[64] stays in registers.
__global__ __launch_bounds__(128, 2)
void gather_qqk(const float* __restrict__ node, const float* __restrict__ piv,
                const float* __restrict__ gamma, const float* __restrict__ beta,
                const float* __restrict__ Wf, const float* __restrict__ bf,
                const float* __restrict__ Wp, const float* __restrict__ bp,
                const float* __restrict__ ipw, const float* __restrict__ ipb,
                const float* __restrict__ wA, const int* __restrict__ idxA,
                float* __restrict__ y, float* __restrict__ Qh, float* __restrict__ Kh) {
  const int b = blockIdx.x >> 5;
  const int ptile = (blockIdx.x & 31) * 8;
  const int t = threadIdx.x;
  __shared__ float qs[8][64];
  __shared__ float ys[8][3];

  if (t < 8) {
    const int p = ptile + t;
    const float g0 = gamma[0], g1 = gamma[1], g2 = gamma[2];
    const float be0 = beta[0], be1 = beta[1], be2 = beta[2];
    float num0 = 0.f, num1 = 0.f, num2 = 0.f, den = 0.f;
#pragma unroll
    for (int k = 0; k < 3; ++k) {
      int idx = idxA[p * 3 + k];
      float w = wA[p * 3 + k];
      const float* r = node + ((size_t)b * NM + idx) * 3;
      float a0 = r[0], a1 = r[1], a2 = r[2];
      float mu = (a0 + a1 + a2) * (1.0f / 3.0f);
      float e0 = a0 - mu, e1 = a1 - mu, e2 = a2 - mu;
      float var = (e0 * e0 + e1 * e1 + e2 * e2) * (1.0f / 3.0f);
      float sc = 1.0f / sqrtf(var + 1e-5f);
      num0 += (e0 * sc * g0 + be0) * w;
      num1 += (e1 * sc * g1 + be1) * w;
      num2 += (e2 * sc * g2 + be2) * w;
      den += w;
    }
    float o0 = num0 / den, o1 = num1 / den, o2 = num2 / den;
    ys[t][0] = o0; ys[t][1] = o1; ys[t][2] = o2;
    float* yr = y + (b * PP + p) * 3;
    yr[0] = o0; yr[1] = o1; yr[2] = o2;   // attn stages y from global
  }
  __syncthreads();

  const int e = t & 63;
  const int half = t >> 6;  // 0 -> Q, 1 -> K
  {
    float wf0 = Wf[e * 3], wf1 = Wf[e * 3 + 1], wf2 = Wf[e * 3 + 2];
    float wp0 = Wp[e * 2], wp1 = Wp[e * 2 + 1];
    float cst = bf[e] + bp[e];
    for (int r = half; r < 8; r += 2) {
      int p = ptile + r;
      float pe = piv[2 * p] * wp0 + piv[2 * p + 1] * wp1;
      qs[r][e] = ys[r][0] * wf0 + ys[r][1] * wf1 + ys[r][2] * wf2 + cst + pe;
    }
  }
  __syncthreads();

  const int row = half * 64 + e;
  float wreg[64];
  const float4* W4 = (const float4*)(ipw + row * 64);
#pragma unroll
  for (int j = 0; j < 16; ++j) {
    float4 v = W4[j];
    wreg[4 * j] = v.x; wreg[4 * j + 1] = v.y; wreg[4 * j + 2] = v.z; wreg[4 * j + 3] = v.w;
  }
  float bias = ipb[row];
  float* dst = half ? Kh : Qh;
  const int h = e >> 4, d = e & 15;
  for (int r = 0; r < 8; ++r) {
    float acc = bias;
#pragma unroll
    for (int j = 0; j < 64; ++j) acc += qs[r][j] * wreg[j];
    int p = ptile + r;
    dst[(((b * 4 + h) * PP) + p) * 16 + d] = acc;
  }
}

// ---------- attention: block = (b, h, q-half); thread = q-row; online softmax ----------
__global__ void attn_kernel(const float* __restrict__ Qh, const float* __restrict__ Kh,
                            const float* __restrict__ y, float* __restrict__ y2) {
  const int b = blockIdx.x >> 3;
  const int h = (blockIdx.x >> 1) & 3;
  const int qh = blockIdx.x & 1;
  const int t = threadIdx.x;          // 128 threads
  const int q = qh * 128 + t;

  __shared__ float Ks[PP * 16];       // 16 KB, head h's K
  __shared__ float ys[PP * 3];        // 3 KB

  {
    const float4* src = (const float4*)(Kh + (size_t)(b * 4 + h) * PP * 16);
    float4* dst = (float4*)Ks;
#pragma unroll
    for (int j = 0; j < 8; ++j) dst[j * 128 + t] = src[j * 128 + t];
    const float* ysrc = y + b * PP * 3;
#pragma unroll
    for (int j = 0; j < 6; ++j) ys[j * 128 + t] = ysrc[j * 128 + t];
  }
  __syncthreads();

  const float4* q4 = (const float4*)(Qh + ((size_t)((b * 4 + h) * PP) + q) * 16);
  float4 qa = q4[0], qb = q4[1], qc = q4[2], qd = q4[3];

  float m = -INF_F, l = 0.f, a0 = 0.f, a1 = 0.f, a2 = 0.f;
#pragma unroll 4
  for (int k = 0; k < PP; ++k) {
    const float4* kr = (const float4*)(Ks + k * 16);   // broadcast read
    float4 k0 = kr[0], k1 = kr[1], k2 = kr[2], k3 = kr[3];
    float dot = qa.x * k0.x + qa.y * k0.y + qa.z * k0.z + qa.w * k0.w
              + qb.x * k1.x + qb.y * k1.y + qb.z * k1.z + qb.w * k1.w
              + qc.x * k2.x + qc.y * k2.y + qc.z * k2.z + qc.w * k2.w
              + qd.x * k3.x + qd.y * k3.y + qd.z * k3.z + qd.w * k3.w;
    float s = dot * 0.25f;            // 1/sqrt(DH=16)
    float mn = fmaxf(m, s);
    float p = __expf(s - mn);
    float sc = __expf(m - mn);
    float y0 = ys[k * 3], y1 = ys[k * 3 + 1], yy2 = ys[k * 3 + 2];
    l = l * sc + p;
    a0 = a0 * sc + p * y0;
    a1 = a1 * sc + p * y1;
    a2 = a2 * sc + p * yy2;
    m = mn;
  }
  float inv = 0.25f / l;              // mean over 4 heads
  float* o = y2 + (b * PP + q) * 3;
  atomicAdd(o + 0, a0 * inv);
  atomicAdd(o + 1, a1 * inv);
  atomicAdd(o + 2, a2 * inv);
}

// ---------- final interp: pure gather + weighted sum + store (KNN precomputed) ----------
__global__ __launch_bounds__(256)
void interp_out(const float* __restrict__ wB, const int* __restrict__ idxB,
                const float* __restrict__ y2, float* __restrict__ out) {
  const int tid = threadIdx.x;
  const int ml = tid & 63;
  const int sub = tid >> 6;          // wave-uniform batch group
  const int m = blockIdx.x * 64 + ml;

  const float w0 = wB[m * 3 + 0], w1 = wB[m * 3 + 1], w2 = wB[m * 3 + 2];
  const int o0 = idxB[m * 3 + 0] * 3, o1 = idxB[m * 3 + 1] * 3, o2 = idxB[m * 3 + 2] * 3;
  const float inv = 1.0f / (w0 + w1 + w2);

#pragma unroll 2
  for (int bi = 0; bi < 8; ++bi) {
    const int b = sub * 8 + bi;                       // wave-uniform
    const float* yb = y2 + b * PP * 3;
    float3 r0 = *(const float3*)(yb + o0);
    float3 r1 = *(const float3*)(yb + o1);
    float3 r2 = *(const float3*)(yb + o2);
    float3 res;
    res.x = (w0 * r0.x + w1 * r1.x + w2 * r2.x) * inv;
    res.y = (w0 * r0.y + w1 * r1.y + w2 * r2.y) * inv;
    res.z = (w0 * r0.z + w1 * r1.z + w2 * r2.z) * inv;
    *(float3*)(out + ((size_t)b * NM + m) * 3) = res; // lane-contiguous 12 B
  }
}

extern "C" void kernel_launch(void* const* d_in, const int* in_sizes, int n_in,
                              void* d_out, int out_size, void* d_ws, size_t ws_size,
                              hipStream_t stream) {
  const float* node  = (const float*)d_in[0];
  const float* mesh  = (const float*)d_in[1];
  const float* piv   = (const float*)d_in[2];
  const float* gamma = (const float*)d_in[3];
  const float* beta  = (const float*)d_in[4];
  const float* Wf    = (const float*)d_in[5];
  const float* bf    = (const float*)d_in[6];
  const float* Wp    = (const float*)d_in[7];
  const float* bp    = (const float*)d_in[8];
  const float* ipw   = (const float*)d_in[9];
  const float* ipb   = (const float*)d_in[10];
  float* out = (float*)d_out;

  // workspace layout (floats)
  float* wA   = (float*)d_ws;                 // PP*3
  int*   idxA = (int*)(wA + PP * 3);          // PP*3
  float* y    = (float*)(idxA + PP * 3);      // BB*PP*3
  float* Qh   = y + BB * PP * 3;              // BB*4*PP*16
  float* Kh   = Qh + BB * PP * 64;            // BB*4*PP*16
  float* y2   = Kh + BB * PP * 64;            // BB*PP*3 (16B-aligned offset)
  float* wB   = y2 + BB * PP * 3;             // NM*3
  int*   idxB = (int*)(wB + NM * 3);          // NM*3

  fused_knn<<<KA_BLOCKS + KB_BLOCKS + 1, 1024, 0, stream>>>(mesh, piv, wA, idxA, wB, idxB, y2);
  gather_qqk<<<BB * 32, 128, 0, stream>>>(node, piv, gamma, beta, Wf, bf, Wp, bp, ipw, ipb,
                                          wA, idxA, y, Qh, Kh);
  attn_kernel<<<BB * 4 * 2, 128, 0, stream>>>(Qh, Kh, y, y2);
  interp_out<<<NM / 64, 256, 0, stream>>>(wB, idxB, y2, out);
}